// Round 6
// baseline (2227.594 us; speedup 1.0000x reference)
//
#include <hip/hip_runtime.h>
#include <hip/hip_fp16.h>

// Problem constants
#define B_   64
#define T_   512
#define I_   128
#define H_   256
#define G4_  1024   // 4*H
#define R_   20
#define DA_  50
#define C_   10

#define NV5  96     // half2 of W per thread resident in VGPRs (k2 0..95)
#define NS5  32     // half2 of W per thread streamed from L2  (k2 96..127)

typedef _Float16 half2_t __attribute__((ext_vector_type(2)));
typedef _Float16 half8_t __attribute__((ext_vector_type(8)));

union U4H { uint4 q; half2_t h[4]; };

__device__ __forceinline__ float fsigmoid(float x) {
  return __fdividef(1.0f, 1.0f + __expf(-x));
}
__device__ __forceinline__ float ftanh(float x) {
  return 1.0f - __fdividef(2.0f, __expf(2.0f * x) + 1.0f);
}

// ---------------------------------------------------------------------------
// K0: pack W_hh [256][1024] fp32 -> Wq[g][k2] half2 (column-major per gate col)
// ---------------------------------------------------------------------------
__global__ __launch_bounds__(256) void k0_pack(const float* __restrict__ Whh,
                                               half2_t* __restrict__ Wq) {
  int idx = blockIdx.x * 256 + threadIdx.x;   // 0..131071
  int g = idx & 1023, k2 = idx >> 10;
  half2_t h;
  h.x = (_Float16)Whh[(2 * k2) * G4_ + g];
  h.y = (_Float16)Whh[(2 * k2 + 1) * G4_ + g];
  Wq[g * 128 + k2] = h;
}

// ---------------------------------------------------------------------------
// K0b: repack streamed W tail into lane-coalesced layout for k5:
// Wt[i*1024 + tid5] = uint4{ Wq[gcol(tid5)*128 + 96+4i .. +3] },  i = 0..7
// where tid5: unit = tid5>>2, gate = tid5&3, gcol = gate*256+unit.
// ---------------------------------------------------------------------------
__global__ __launch_bounds__(256) void k0b_packtail(const half2_t* __restrict__ Wq,
                                                    uint4* __restrict__ Wt) {
  int j = blockIdx.x * 256 + threadIdx.x;   // 0..8191
  int i = j >> 10, tid5 = j & 1023;
  int unit = tid5 >> 2, gate = tid5 & 3;
  int gcol = gate * 256 + unit;
  Wt[j] = *(const uint4*)(Wq + (size_t)gcol * 128 + NV5 + 4 * i);
}

// ---------------------------------------------------------------------------
// K1: S = (tanh(x@W1^T + b1))@W2^T + b2, layout S[B,R,T].
// ---------------------------------------------------------------------------
__global__ __launch_bounds__(256) void k1_scores(const float* __restrict__ x,
                                                 const float* __restrict__ W1,
                                                 const float* __restrict__ b1,
                                                 const float* __restrict__ W2,
                                                 const float* __restrict__ b2,
                                                 float* __restrict__ S) {
  __shared__ float xs[64][129];
  __shared__ float w1s[128][64];
  __shared__ float a1s[64][53];
  int blk = blockIdx.x;
  int tid = threadIdx.x;
  int row0 = blk * 64;
  const float4* xv = (const float4*)(x + (size_t)row0 * I_);
#pragma unroll
  for (int ch = 0; ch < 8; ch++) {
    int fidx = ch * 256 + tid;
    int r = fidx >> 5, k4 = (fidx & 31) << 2;
    float4 f = xv[fidx];
    xs[r][k4] = f.x; xs[r][k4 + 1] = f.y; xs[r][k4 + 2] = f.z; xs[r][k4 + 3] = f.w;
  }
  const float4* w1v = (const float4*)W1;
#pragma unroll
  for (int ch = 0; ch < 7; ch++) {
    int fidx = ch * 256 + tid;
    if (fidx < 1600) {
      int d = fidx >> 5, k4 = (fidx & 31) << 2;
      float4 f = w1v[fidx];
      w1s[k4][d] = f.x; w1s[k4 + 1][d] = f.y; w1s[k4 + 2][d] = f.z; w1s[k4 + 3][d] = f.w;
    }
  }
  __syncthreads();
  int ty = tid >> 4, tx = tid & 15;
  float acc[4][4] = {};
#pragma unroll 4
  for (int k = 0; k < I_; k++) {
    float a0 = xs[4 * ty][k], a1 = xs[4 * ty + 1][k];
    float a2 = xs[4 * ty + 2][k], a3 = xs[4 * ty + 3][k];
    float4 bq = *(const float4*)&w1s[k][tx << 2];
    acc[0][0] += a0 * bq.x; acc[0][1] += a0 * bq.y; acc[0][2] += a0 * bq.z; acc[0][3] += a0 * bq.w;
    acc[1][0] += a1 * bq.x; acc[1][1] += a1 * bq.y; acc[1][2] += a1 * bq.z; acc[1][3] += a1 * bq.w;
    acc[2][0] += a2 * bq.x; acc[2][1] += a2 * bq.y; acc[2][2] += a2 * bq.z; acc[2][3] += a2 * bq.w;
    acc[3][0] += a3 * bq.x; acc[3][1] += a3 * bq.y; acc[3][2] += a3 * bq.z; acc[3][3] += a3 * bq.w;
  }
#pragma unroll
  for (int i = 0; i < 4; i++) {
#pragma unroll
    for (int j = 0; j < 4; j++) {
      int col = (tx << 2) + j;
      if (col < DA_) a1s[4 * ty + i][col] = tanhf(acc[i][j] + b1[col]);
    }
  }
  __syncthreads();
  int row = tid & 63, rq = tid >> 6;
  int bt = row0 + row;
  int b = bt >> 9, t = bt & 511;
#pragma unroll
  for (int m = 0; m < 5; m++) {
    int r = rq + (m << 2);
    float acc2 = b2[r];
#pragma unroll 10
    for (int d = 0; d < DA_; d++) acc2 += a1s[row][d] * W2[r * DA_ + d];
    S[((size_t)(b * R_ + r)) * T_ + t] = acc2;
  }
}

// ---------------------------------------------------------------------------
// K2: per (b,r): m = max_t S; E = exp(S-m); invd[t] = 1/cumsum(E)[t]
// ---------------------------------------------------------------------------
__global__ __launch_bounds__(64) void k2_prefix(const float* __restrict__ S,
                                                float* __restrict__ E,
                                                float* __restrict__ invd) {
  int br = blockIdx.x;
  int l = threadIdx.x;
  const float* Sr = S + (size_t)br * T_;
  float v[8];
  float m = -1e30f;
#pragma unroll
  for (int c = 0; c < 8; c++) {
    v[c] = Sr[c * 64 + l];
    m = fmaxf(m, v[c]);
  }
#pragma unroll
  for (int off = 32; off; off >>= 1) m = fmaxf(m, __shfl_xor(m, off));
  float carry = 0.f;
  for (int c = 0; c < 8; c++) {
    float e = expf(v[c] - m);
    float s = e;
#pragma unroll
    for (int off = 1; off < 64; off <<= 1) {
      float u = __shfl_up(s, off);
      if (l >= off) s += u;
    }
    E[(size_t)br * T_ + c * 64 + l] = e;
    invd[(size_t)br * T_ + c * 64 + l] = 1.f / (carry + s);
    carry += __shfl(s, 63);
  }
}

// ---------------------------------------------------------------------------
// K3a: per (b, chunk): P[b][c][r][i] = sum_{t in chunk} E[b,r,t] * x[b,t,i]
// ---------------------------------------------------------------------------
__global__ __launch_bounds__(128) void k3a(const float* __restrict__ x,
                                           const float* __restrict__ E,
                                           float* __restrict__ P) {
  int b = blockIdx.x >> 3, c = blockIdx.x & 7;
  int i = threadIdx.x;
  int t0 = c * 64;
  __shared__ float es[2][R_];
  float acc[R_];
#pragma unroll
  for (int r = 0; r < R_; r++) acc[r] = 0.f;
  float rE = 0.f;
  if (i < R_) rE = E[((size_t)(b * R_ + i)) * T_ + t0];
  const float* xb = x + (size_t)b * T_ * I_;
  float xv = xb[(size_t)t0 * I_ + i];
  int buf = 0;
  for (int tt = 0; tt < 64; tt++) {
    if (i < R_) es[buf][i] = rE;
    __syncthreads();
    if (tt + 1 < 64) {
      if (i < R_) rE = E[((size_t)(b * R_ + i)) * T_ + t0 + tt + 1];
    }
    float xcur = xv;
    if (tt + 1 < 64) xv = xb[(size_t)(t0 + tt + 1) * I_ + i];
#pragma unroll
    for (int r = 0; r < R_; r++) acc[r] += es[buf][r] * xcur;
    buf ^= 1;
  }
#pragma unroll
  for (int r = 0; r < R_; r++)
    P[(size_t)((b * 8 + c) * R_ + r) * I_ + i] = acc[r];
}

// ---------------------------------------------------------------------------
// K3b: exclusive prefix of P over chunks, per (b,r,i). In place.
// ---------------------------------------------------------------------------
__global__ __launch_bounds__(256) void k3b(float* __restrict__ P) {
  int gid = blockIdx.x * 256 + threadIdx.x;
  int i = gid & 127;
  int r = (gid >> 7) % R_;
  int b = gid / (R_ * I_);
  float s = 0.f;
#pragma unroll
  for (int c = 0; c < 8; c++) {
    size_t idx = (size_t)((b * 8 + c) * R_ + r) * I_ + i;
    float v = P[idx];
    P[idx] = s;
    s += v;
  }
}

// ---------------------------------------------------------------------------
// K3c: per (b, chunk): acc init from P prefix, then 64 steps producing M.
// ---------------------------------------------------------------------------
__global__ __launch_bounds__(128) void k3c(const float* __restrict__ x,
                                           const float* __restrict__ E,
                                           const float* __restrict__ invd,
                                           const float* __restrict__ P,
                                           float* __restrict__ M) {
  int b = blockIdx.x >> 3, c = blockIdx.x & 7;
  int i = threadIdx.x;
  int t0 = c * 64;
  __shared__ float es[2][R_], ds[2][R_];
  float acc[R_];
#pragma unroll
  for (int r = 0; r < R_; r++)
    acc[r] = P[(size_t)((b * 8 + c) * R_ + r) * I_ + i];
  float rE = 0.f, rD = 0.f;
  if (i < R_)
    rE = E[((size_t)(b * R_ + i)) * T_ + t0];
  else if (i < 2 * R_)
    rD = invd[((size_t)(b * R_ + (i - R_))) * T_ + t0];
  const float* xb = x + (size_t)b * T_ * I_;
  float xv = xb[(size_t)t0 * I_ + i];
  int buf = 0;
  for (int tt = 0; tt < 64; tt++) {
    if (i < R_) es[buf][i] = rE;
    else if (i < 2 * R_) ds[buf][i - R_] = rD;
    __syncthreads();
    if (tt + 1 < 64) {
      if (i < R_)
        rE = E[((size_t)(b * R_ + i)) * T_ + t0 + tt + 1];
      else if (i < 2 * R_)
        rD = invd[((size_t)(b * R_ + (i - R_))) * T_ + t0 + tt + 1];
    }
    float xcur = xv;
    if (tt + 1 < 64) xv = xb[(size_t)(t0 + tt + 1) * I_ + i];
    float s = 0.f;
#pragma unroll
    for (int r = 0; r < R_; r++) {
      acc[r] += es[buf][r] * xcur;
      s += acc[r] * ds[buf][r];
    }
    M[(size_t)b * T_ * I_ + (size_t)(t0 + tt) * I_ + i] = s * (1.0f / R_);
    buf ^= 1;
  }
}

// ---------------------------------------------------------------------------
// K4: gx[row][perm(col)] = M[row,:] @ W_ih[:,col] + b[col].  Output fp16.
// perm(col) = (col&255)*4 + (col>>8)  == k5's thread slot for that column,
// so k5's per-step gx read is lane-coalesced.
// ---------------------------------------------------------------------------
__global__ __launch_bounds__(256) void k4_gemm(const float* __restrict__ Mm,
                                               const float* __restrict__ Wih,
                                               const float* __restrict__ bg,
                                               __half* __restrict__ gx) {
  __shared__ float As[I_][64];
  __shared__ float Bs[I_][64];
  int row0 = blockIdx.x * 64, col0 = blockIdx.y * 64;
  int tid = threadIdx.x;
#pragma unroll
  for (int ch = 0; ch < 8; ch++) {
    int fidx = ch * 256 + tid;
    int r = fidx >> 5;
    int kk = (fidx & 31) << 2;
    float4 f = ((const float4*)(Mm + (size_t)(row0 + r) * I_))[fidx & 31];
    As[kk + 0][r] = f.x;
    As[kk + 1][r] = f.y;
    As[kk + 2][r] = f.z;
    As[kk + 3][r] = f.w;
  }
#pragma unroll
  for (int ch = 0; ch < 8; ch++) {
    int fidx = ch * 256 + tid;
    int k = fidx >> 4;
    int c4 = (fidx & 15) << 2;
    float4 f = *((const float4*)(Wih + (size_t)k * G4_ + col0 + c4));
    *((float4*)&Bs[k][c4]) = f;
  }
  __syncthreads();
  int ty = tid >> 4, tx = tid & 15;
  float acc[4][4] = {};
#pragma unroll 4
  for (int k = 0; k < I_; k++) {
    float4 a = *((float4*)&As[k][ty << 2]);
    float4 bq = *((float4*)&Bs[k][tx << 2]);
    acc[0][0] += a.x * bq.x; acc[0][1] += a.x * bq.y; acc[0][2] += a.x * bq.z; acc[0][3] += a.x * bq.w;
    acc[1][0] += a.y * bq.x; acc[1][1] += a.y * bq.y; acc[1][2] += a.y * bq.z; acc[1][3] += a.y * bq.w;
    acc[2][0] += a.z * bq.x; acc[2][1] += a.z * bq.y; acc[2][2] += a.z * bq.z; acc[2][3] += a.z * bq.w;
    acc[3][0] += a.w * bq.x; acc[3][1] += a.w * bq.y; acc[3][2] += a.w * bq.z; acc[3][3] += a.w * bq.w;
  }
#pragma unroll
  for (int ii = 0; ii < 4; ii++) {
#pragma unroll
    for (int jj = 0; jj < 4; jj++) {
      int row = row0 + (ty << 2) + ii;
      int col = col0 + (tx << 2) + jj;
      int perm = ((col & 255) << 2) | (col >> 8);
      gx[(size_t)row * G4_ + perm] = __float2half(acc[ii][jj] + bg[col]);
    }
  }
}

// ---------------------------------------------------------------------------
// K5: LSTM scan, ONE 1024-thread block per b — no cross-CU communication.
// thread: unit = tid>>2, gate = tid&3, gcol = gate*256+unit (full K=256 dot).
// W: 96 half2/thread VGPR-resident (laundered via asm so the per-step
// barrier can't force reloads) + 32 half2/thread streamed from L2 each step
// in lane-coalesced layout Wt[i][tid]. h double-buffered in LDS (1 KB),
// ONE __syncthreads per step; gate gather via wave-local shfl_down.
// amdgpu_waves_per_eu(4,4) pins the allocator to the 128-VGPR budget.
// ---------------------------------------------------------------------------
__global__ __launch_bounds__(1024)
__attribute__((amdgpu_waves_per_eu(4, 4)))
void k5_lstm(const __half* __restrict__ gx, const half2_t* __restrict__ Wq,
             const uint4* __restrict__ Wt, float* __restrict__ hT) {
  int b = blockIdx.x;
  int tid = threadIdx.x;
  int unit = tid >> 2, gate = tid & 3;
  int gcol = gate * 256 + unit;

  __shared__ __align__(16) unsigned hsU[2][128];   // h fp16 double-buffer

  // ---- W: VGPR part (k2 0..95), loaded once then laundered ----
  union { unsigned u[NV5]; half2_t h[NV5]; uint4 q[NV5 / 4]; } w;
  {
    const uint4* wp = (const uint4*)(Wq + (size_t)gcol * 128);
#pragma unroll
    for (int i = 0; i < NV5 / 4; i++) w.q[i] = wp[i];
  }
#pragma unroll
  for (int j = 0; j < NV5; j++) asm volatile("" : "+v"(w.u[j]));

  if (tid < 128) hsU[0][tid] = 0x3C003C00u;        // h0 = 1.0 pairs

  float cstate = 1.0f;                             // leaders (tid&3)==0
  const __half* gp = gx + (size_t)b * T_ * G4_ + tid;  // permuted layout

  for (int t = 0; t < T_; t++) {
    __syncthreads();
    // stream tail W (L2-resident, coalesced) + gate input
    uint4 tw[NS5 / 4];
#pragma unroll
    for (int i = 0; i < NS5 / 4; i++) tw[i] = Wt[i * 1024 + tid];
    float gxv = (float)*gp;
    gp += G4_;

    const half2_t* hb = (const half2_t*)hsU[t & 1];
    float a0 = 0.f, a1 = 0.f, a2 = 0.f, a3 = 0.f;
#pragma unroll
    for (int i = 0; i < NV5 / 4; i++) {            // k2 = 4i..4i+3 (0..95)
      half8_t hv = *(const half8_t*)(hb + i * 4);
      a0 = __builtin_amdgcn_fdot2(w.h[4 * i + 0], ((half2_t*)&hv)[0], a0, false);
      a1 = __builtin_amdgcn_fdot2(w.h[4 * i + 1], ((half2_t*)&hv)[1], a1, false);
      a2 = __builtin_amdgcn_fdot2(w.h[4 * i + 2], ((half2_t*)&hv)[2], a2, false);
      a3 = __builtin_amdgcn_fdot2(w.h[4 * i + 3], ((half2_t*)&hv)[3], a3, false);
    }
#pragma unroll
    for (int i = 0; i < NS5 / 4; i++) {            // k2 = 96+4i..99+4i
      half8_t hv = *(const half8_t*)(hb + NV5 + i * 4);
      U4H c; c.q = tw[i];
      a0 = __builtin_amdgcn_fdot2(c.h[0], ((half2_t*)&hv)[0], a0, false);
      a1 = __builtin_amdgcn_fdot2(c.h[1], ((half2_t*)&hv)[1], a1, false);
      a2 = __builtin_amdgcn_fdot2(c.h[2], ((half2_t*)&hv)[2], a2, false);
      a3 = __builtin_amdgcn_fdot2(c.h[3], ((half2_t*)&hv)[3], a3, false);
    }
    float s = ((a0 + a1) + (a2 + a3)) + gxv;

    // gate gather: gates 0..3 of a unit sit in adjacent lanes
    float s1 = __shfl_down(s, 1);
    float s2 = __shfl_down(s, 2);
    float s3 = __shfl_down(s, 3);
    if ((tid & 3) == 0) {
      float vi = fsigmoid(s);
      float vf = fsigmoid(s1);
      float vg = ftanh(s2);
      float vo = fsigmoid(s3);
      cstate = vf * cstate + vi * vg;
      float h = vo * ftanh(cstate);
      ((__half*)hsU[(t + 1) & 1])[unit] = __float2half(h);
      if (t == T_ - 1) hT[b * H_ + unit] = h;
    }
  }
}

// ---------------------------------------------------------------------------
// K6: logits = hT @ Wfc^T + bfc; softmax.  One wave per b.
// ---------------------------------------------------------------------------
__global__ __launch_bounds__(64) void k6_head(const float* __restrict__ hT,
                                              const float* __restrict__ Wfc,
                                              const float* __restrict__ bfc,
                                              float* __restrict__ out) {
  int b = blockIdx.x, l = threadIdx.x;
  const float* h = hT + b * H_;
  float p[C_];
#pragma unroll
  for (int c = 0; c < C_; c++) p[c] = 0.f;
#pragma unroll
  for (int q = 0; q < 4; q++) {
    float hv = h[q * 64 + l];
#pragma unroll
    for (int c = 0; c < C_; c++) p[c] += hv * Wfc[c * H_ + q * 64 + l];
  }
#pragma unroll
  for (int c = 0; c < C_; c++)
    for (int off = 32; off; off >>= 1) p[c] += __shfl_xor(p[c], off);
  if (l == 0) {
    float m = -1e30f, e[C_], sum = 0.f;
    for (int c = 0; c < C_; c++) { p[c] += bfc[c]; m = fmaxf(m, p[c]); }
    for (int c = 0; c < C_; c++) { e[c] = expf(p[c] - m); sum += e[c]; }
    for (int c = 0; c < C_; c++) out[b * C_ + c] = e[c] / sum;
  }
}

// ---------------------------------------------------------------------------
// Workspace layout (float offsets):
//   S     [B,R,T]        wsf + 0        (dead after k2; Wt aliases it)
//   Wt    [8][1024]uint4 wsf + 0        (32768 dwords; written by k0b post-k2)
//   E     [B,R,T]        wsf + 655360
//   INVD  [B,R,T]        wsf + 1310720
//   M     [B,T,I]        wsf + 1966080
//   hT    [B,H]          wsf + 6160384
//   Wq    [1024][128]h2  wsf + 6176768  (131072 dwords)
//   gx    [B,T,4H] fp16  wsf + 6307840  (16777216 dwords)
//   P     [B][8][R][I]   aliases gx region (P dead before k4 writes gx)
// ---------------------------------------------------------------------------
extern "C" void kernel_launch(void* const* d_in, const int* in_sizes, int n_in,
                              void* d_out, int out_size, void* d_ws, size_t ws_size,
                              hipStream_t stream) {
  const float* x   = (const float*)d_in[0];
  const float* Wih = (const float*)d_in[1];
  const float* Whh = (const float*)d_in[2];
  const float* bg  = (const float*)d_in[3];
  const float* W1  = (const float*)d_in[4];
  const float* b1  = (const float*)d_in[5];
  const float* W2  = (const float*)d_in[6];
  const float* b2  = (const float*)d_in[7];
  const float* Wfc = (const float*)d_in[8];
  const float* bfc = (const float*)d_in[9];
  float* out = (float*)d_out;

  float* wsf = (float*)d_ws;
  float* S    = wsf;
  uint4* Wt   = (uint4*)wsf;             // aliases S (S dead after k2)
  float* E    = wsf + 655360;
  float* INVD = wsf + 1310720;
  float* Mm   = wsf + 1966080;
  float* hT   = wsf + 6160384;
  half2_t* Wq = (half2_t*)(wsf + 6176768);
  __half* gx  = (__half*)(wsf + 6307840);
  float* P    = wsf + 6307840;           // aliases gx region (disjoint in time)

  hipLaunchKernelGGL(k0_pack,     dim3(512),     dim3(256),  0, stream, Whh, Wq);
  hipLaunchKernelGGL(k1_scores,   dim3(512),     dim3(256),  0, stream, x, W1, b1, W2, b2, S);
  hipLaunchKernelGGL(k2_prefix,   dim3(B_ * R_), dim3(64),   0, stream, S, E, INVD);
  hipLaunchKernelGGL(k0b_packtail,dim3(32),      dim3(256),  0, stream, Wq, Wt);
  hipLaunchKernelGGL(k3a,         dim3(512),     dim3(128),  0, stream, x, E, P);
  hipLaunchKernelGGL(k3b,         dim3(640),     dim3(256),  0, stream, P);
  hipLaunchKernelGGL(k3c,         dim3(512),     dim3(128),  0, stream, x, E, INVD, P, Mm);
  hipLaunchKernelGGL(k4_gemm,     dim3(512, 16), dim3(256),  0, stream, Mm, Wih, bg, gx);
  hipLaunchKernelGGL(k5_lstm,     dim3(B_),      dim3(1024), 0, stream, gx, Wq, Wt, hT);
  hipLaunchKernelGGL(k6_head,     dim3(B_),      dim3(64),   0, stream, hT, Wfc, bfc, out);
}

// Round 7
// 1576.677 us; speedup vs baseline: 1.4128x; 1.4128x over previous
//
#include <hip/hip_runtime.h>
#include <hip/hip_fp16.h>

// Problem constants
#define B_   64
#define T_   512
#define I_   128
#define H_   256
#define G4_  1024   // 4*H
#define R_   20
#define DA_  50
#define C_   10

typedef _Float16 half2_t __attribute__((ext_vector_type(2)));
typedef _Float16 half8_t __attribute__((ext_vector_type(8)));

union U4H { uint4 q; half2_t h[4]; };

__device__ __forceinline__ float fsigmoid(float x) {
  return __fdividef(1.0f, 1.0f + __expf(-x));
}
__device__ __forceinline__ float ftanh(float x) {
  return 1.0f - __fdividef(2.0f, __expf(2.0f * x) + 1.0f);
}

// ---------------------------------------------------------------------------
// K0: pack W_hh [256][1024] fp32 -> Wq[g][k2] half2 (column-major per gate col)
// ---------------------------------------------------------------------------
__global__ __launch_bounds__(256) void k0_pack(const float* __restrict__ Whh,
                                               half2_t* __restrict__ Wq) {
  int idx = blockIdx.x * 256 + threadIdx.x;   // 0..131071
  int g = idx & 1023, k2 = idx >> 10;
  half2_t h;
  h.x = (_Float16)Whh[(2 * k2) * G4_ + g];
  h.y = (_Float16)Whh[(2 * k2 + 1) * G4_ + g];
  Wq[g * 128 + k2] = h;
}

// ---------------------------------------------------------------------------
// K0b: repack W into k5's lane-coalesced chunk layout:
// WP[i*1024 + t] = uint4{ Wq[gcol(t)*128 + 4i .. 4i+3] },  i = 0..31,
// gcol(t) = (t&3)*256 + (t>>2)   (t = k5 thread id; unit=t>>2, gate=t&3)
// Chunks 0..7 -> k5 LDS-resident part; chunks 8..31 -> streamed from L2.
// ---------------------------------------------------------------------------
__global__ __launch_bounds__(256) void k0b_pack(const half2_t* __restrict__ Wq,
                                                uint4* __restrict__ WP) {
  int j = blockIdx.x * 256 + threadIdx.x;   // 0..32767
  int i = j >> 10, t = j & 1023;
  int gcol = (t & 3) * 256 + (t >> 2);
  WP[j] = *(const uint4*)(Wq + (size_t)gcol * 128 + 4 * i);
}

// ---------------------------------------------------------------------------
// K1: S = (tanh(x@W1^T + b1))@W2^T + b2, layout S[B,R,T].
// ---------------------------------------------------------------------------
__global__ __launch_bounds__(256) void k1_scores(const float* __restrict__ x,
                                                 const float* __restrict__ W1,
                                                 const float* __restrict__ b1,
                                                 const float* __restrict__ W2,
                                                 const float* __restrict__ b2,
                                                 float* __restrict__ S) {
  __shared__ float xs[64][129];
  __shared__ float w1s[128][64];
  __shared__ float a1s[64][53];
  int blk = blockIdx.x;
  int tid = threadIdx.x;
  int row0 = blk * 64;
  const float4* xv = (const float4*)(x + (size_t)row0 * I_);
#pragma unroll
  for (int ch = 0; ch < 8; ch++) {
    int fidx = ch * 256 + tid;
    int r = fidx >> 5, k4 = (fidx & 31) << 2;
    float4 f = xv[fidx];
    xs[r][k4] = f.x; xs[r][k4 + 1] = f.y; xs[r][k4 + 2] = f.z; xs[r][k4 + 3] = f.w;
  }
  const float4* w1v = (const float4*)W1;
#pragma unroll
  for (int ch = 0; ch < 7; ch++) {
    int fidx = ch * 256 + tid;
    if (fidx < 1600) {
      int d = fidx >> 5, k4 = (fidx & 31) << 2;
      float4 f = w1v[fidx];
      w1s[k4][d] = f.x; w1s[k4 + 1][d] = f.y; w1s[k4 + 2][d] = f.z; w1s[k4 + 3][d] = f.w;
    }
  }
  __syncthreads();
  int ty = tid >> 4, tx = tid & 15;
  float acc[4][4] = {};
#pragma unroll 4
  for (int k = 0; k < I_; k++) {
    float a0 = xs[4 * ty][k], a1 = xs[4 * ty + 1][k];
    float a2 = xs[4 * ty + 2][k], a3 = xs[4 * ty + 3][k];
    float4 bq = *(const float4*)&w1s[k][tx << 2];
    acc[0][0] += a0 * bq.x; acc[0][1] += a0 * bq.y; acc[0][2] += a0 * bq.z; acc[0][3] += a0 * bq.w;
    acc[1][0] += a1 * bq.x; acc[1][1] += a1 * bq.y; acc[1][2] += a1 * bq.z; acc[1][3] += a1 * bq.w;
    acc[2][0] += a2 * bq.x; acc[2][1] += a2 * bq.y; acc[2][2] += a2 * bq.z; acc[2][3] += a2 * bq.w;
    acc[3][0] += a3 * bq.x; acc[3][1] += a3 * bq.y; acc[3][2] += a3 * bq.z; acc[3][3] += a3 * bq.w;
  }
#pragma unroll
  for (int i = 0; i < 4; i++) {
#pragma unroll
    for (int j = 0; j < 4; j++) {
      int col = (tx << 2) + j;
      if (col < DA_) a1s[4 * ty + i][col] = tanhf(acc[i][j] + b1[col]);
    }
  }
  __syncthreads();
  int row = tid & 63, rq = tid >> 6;
  int bt = row0 + row;
  int b = bt >> 9, t = bt & 511;
#pragma unroll
  for (int m = 0; m < 5; m++) {
    int r = rq + (m << 2);
    float acc2 = b2[r];
#pragma unroll 10
    for (int d = 0; d < DA_; d++) acc2 += a1s[row][d] * W2[r * DA_ + d];
    S[((size_t)(b * R_ + r)) * T_ + t] = acc2;
  }
}

// ---------------------------------------------------------------------------
// K2: per (b,r): m = max_t S; E = exp(S-m); invd[t] = 1/cumsum(E)[t]
// ---------------------------------------------------------------------------
__global__ __launch_bounds__(64) void k2_prefix(const float* __restrict__ S,
                                                float* __restrict__ E,
                                                float* __restrict__ invd) {
  int br = blockIdx.x;
  int l = threadIdx.x;
  const float* Sr = S + (size_t)br * T_;
  float v[8];
  float m = -1e30f;
#pragma unroll
  for (int c = 0; c < 8; c++) {
    v[c] = Sr[c * 64 + l];
    m = fmaxf(m, v[c]);
  }
#pragma unroll
  for (int off = 32; off; off >>= 1) m = fmaxf(m, __shfl_xor(m, off));
  float carry = 0.f;
  for (int c = 0; c < 8; c++) {
    float e = expf(v[c] - m);
    float s = e;
#pragma unroll
    for (int off = 1; off < 64; off <<= 1) {
      float u = __shfl_up(s, off);
      if (l >= off) s += u;
    }
    E[(size_t)br * T_ + c * 64 + l] = e;
    invd[(size_t)br * T_ + c * 64 + l] = 1.f / (carry + s);
    carry += __shfl(s, 63);
  }
}

// ---------------------------------------------------------------------------
// K3a: per (b, chunk): P[b][c][r][i] = sum_{t in chunk} E[b,r,t] * x[b,t,i]
// ---------------------------------------------------------------------------
__global__ __launch_bounds__(128) void k3a(const float* __restrict__ x,
                                           const float* __restrict__ E,
                                           float* __restrict__ P) {
  int b = blockIdx.x >> 3, c = blockIdx.x & 7;
  int i = threadIdx.x;
  int t0 = c * 64;
  __shared__ float es[2][R_];
  float acc[R_];
#pragma unroll
  for (int r = 0; r < R_; r++) acc[r] = 0.f;
  float rE = 0.f;
  if (i < R_) rE = E[((size_t)(b * R_ + i)) * T_ + t0];
  const float* xb = x + (size_t)b * T_ * I_;
  float xv = xb[(size_t)t0 * I_ + i];
  int buf = 0;
  for (int tt = 0; tt < 64; tt++) {
    if (i < R_) es[buf][i] = rE;
    __syncthreads();
    if (tt + 1 < 64) {
      if (i < R_) rE = E[((size_t)(b * R_ + i)) * T_ + t0 + tt + 1];
    }
    float xcur = xv;
    if (tt + 1 < 64) xv = xb[(size_t)(t0 + tt + 1) * I_ + i];
#pragma unroll
    for (int r = 0; r < R_; r++) acc[r] += es[buf][r] * xcur;
    buf ^= 1;
  }
#pragma unroll
  for (int r = 0; r < R_; r++)
    P[(size_t)((b * 8 + c) * R_ + r) * I_ + i] = acc[r];
}

// ---------------------------------------------------------------------------
// K3b: exclusive prefix of P over chunks, per (b,r,i). In place.
// ---------------------------------------------------------------------------
__global__ __launch_bounds__(256) void k3b(float* __restrict__ P) {
  int gid = blockIdx.x * 256 + threadIdx.x;
  int i = gid & 127;
  int r = (gid >> 7) % R_;
  int b = gid / (R_ * I_);
  float s = 0.f;
#pragma unroll
  for (int c = 0; c < 8; c++) {
    size_t idx = (size_t)((b * 8 + c) * R_ + r) * I_ + i;
    float v = P[idx];
    P[idx] = s;
    s += v;
  }
}

// ---------------------------------------------------------------------------
// K3c: per (b, chunk): acc init from P prefix, then 64 steps producing M.
// ---------------------------------------------------------------------------
__global__ __launch_bounds__(128) void k3c(const float* __restrict__ x,
                                           const float* __restrict__ E,
                                           const float* __restrict__ invd,
                                           const float* __restrict__ P,
                                           float* __restrict__ M) {
  int b = blockIdx.x >> 3, c = blockIdx.x & 7;
  int i = threadIdx.x;
  int t0 = c * 64;
  __shared__ float es[2][R_], ds[2][R_];
  float acc[R_];
#pragma unroll
  for (int r = 0; r < R_; r++)
    acc[r] = P[(size_t)((b * 8 + c) * R_ + r) * I_ + i];
  float rE = 0.f, rD = 0.f;
  if (i < R_)
    rE = E[((size_t)(b * R_ + i)) * T_ + t0];
  else if (i < 2 * R_)
    rD = invd[((size_t)(b * R_ + (i - R_))) * T_ + t0];
  const float* xb = x + (size_t)b * T_ * I_;
  float xv = xb[(size_t)t0 * I_ + i];
  int buf = 0;
  for (int tt = 0; tt < 64; tt++) {
    if (i < R_) es[buf][i] = rE;
    else if (i < 2 * R_) ds[buf][i - R_] = rD;
    __syncthreads();
    if (tt + 1 < 64) {
      if (i < R_)
        rE = E[((size_t)(b * R_ + i)) * T_ + t0 + tt + 1];
      else if (i < 2 * R_)
        rD = invd[((size_t)(b * R_ + (i - R_))) * T_ + t0 + tt + 1];
    }
    float xcur = xv;
    if (tt + 1 < 64) xv = xb[(size_t)(t0 + tt + 1) * I_ + i];
    float s = 0.f;
#pragma unroll
    for (int r = 0; r < R_; r++) {
      acc[r] += es[buf][r] * xcur;
      s += acc[r] * ds[buf][r];
    }
    M[(size_t)b * T_ * I_ + (size_t)(t0 + tt) * I_ + i] = s * (1.0f / R_);
    buf ^= 1;
  }
}

// ---------------------------------------------------------------------------
// K4: gx[row][perm(col)] = M[row,:] @ W_ih[:,col] + b[col].  Output fp16.
// perm(col) = (col&255)*4 + (col>>8) == k5's thread slot for that column.
// ---------------------------------------------------------------------------
__global__ __launch_bounds__(256) void k4_gemm(const float* __restrict__ Mm,
                                               const float* __restrict__ Wih,
                                               const float* __restrict__ bg,
                                               __half* __restrict__ gx) {
  __shared__ float As[I_][64];
  __shared__ float Bs[I_][64];
  int row0 = blockIdx.x * 64, col0 = blockIdx.y * 64;
  int tid = threadIdx.x;
#pragma unroll
  for (int ch = 0; ch < 8; ch++) {
    int fidx = ch * 256 + tid;
    int r = fidx >> 5;
    int kk = (fidx & 31) << 2;
    float4 f = ((const float4*)(Mm + (size_t)(row0 + r) * I_))[fidx & 31];
    As[kk + 0][r] = f.x;
    As[kk + 1][r] = f.y;
    As[kk + 2][r] = f.z;
    As[kk + 3][r] = f.w;
  }
#pragma unroll
  for (int ch = 0; ch < 8; ch++) {
    int fidx = ch * 256 + tid;
    int k = fidx >> 4;
    int c4 = (fidx & 15) << 2;
    float4 f = *((const float4*)(Wih + (size_t)k * G4_ + col0 + c4));
    *((float4*)&Bs[k][c4]) = f;
  }
  __syncthreads();
  int ty = tid >> 4, tx = tid & 15;
  float acc[4][4] = {};
#pragma unroll 4
  for (int k = 0; k < I_; k++) {
    float4 a = *((float4*)&As[k][ty << 2]);
    float4 bq = *((float4*)&Bs[k][tx << 2]);
    acc[0][0] += a.x * bq.x; acc[0][1] += a.x * bq.y; acc[0][2] += a.x * bq.z; acc[0][3] += a.x * bq.w;
    acc[1][0] += a.y * bq.x; acc[1][1] += a.y * bq.y; acc[1][2] += a.y * bq.z; acc[1][3] += a.y * bq.w;
    acc[2][0] += a.z * bq.x; acc[2][1] += a.z * bq.y; acc[2][2] += a.z * bq.z; acc[2][3] += a.z * bq.w;
    acc[3][0] += a.w * bq.x; acc[3][1] += a.w * bq.y; acc[3][2] += a.w * bq.z; acc[3][3] += a.w * bq.w;
  }
#pragma unroll
  for (int ii = 0; ii < 4; ii++) {
#pragma unroll
    for (int jj = 0; jj < 4; jj++) {
      int row = row0 + (ty << 2) + ii;
      int col = col0 + (tx << 2) + jj;
      int perm = ((col & 255) << 2) | (col >> 8);
      gx[(size_t)row * G4_ + perm] = __float2half(acc[ii][jj] + bg[col]);
    }
  }
}

// ---------------------------------------------------------------------------
// K5: LSTM scan, ONE 1024-thread block per b (no cross-CU traffic, no
// register-resident W). Thread = one gate column (unit=tid>>2, gate=tid&3).
// W split: chunks 0..7 (k2 0..31) LDS-resident (128 KB, loaded once);
// chunks 8..31 streamed from L2 every step, lane-coalesced WP[i][tid],
// software-pipelined in 3 groups of 8 uint4 (<=64 VGPRs in flight).
// h double-buffered in LDS; ONE __syncthreads per step.
// Per-XCD stream budget: 8 blk x 384 KB = 3 MB/step -> ~700ns (L2-BW bound).
// ---------------------------------------------------------------------------
__global__ __launch_bounds__(1024) void k5_lstm(const __half* __restrict__ gx,
                                                const uint4* __restrict__ WP,
                                                float* __restrict__ hT) {
  int b = blockIdx.x;
  int tid = threadIdx.x;
  int unit = tid >> 2;                  // 0..255

  __shared__ __align__(16) unsigned hsU[2][128];   // h fp16 double-buffer
  __shared__ __align__(16) uint4 wl[8 * 1024];     // W chunks 0..7, 128 KB

  // one-time LDS fill (coalesced; lane-contiguous layout -> conflict-free)
#pragma unroll
  for (int i = 0; i < 8; i++) wl[i * 1024 + tid] = WP[i * 1024 + tid];
  if (tid < 128) hsU[0][tid] = 0x3C003C00u;        // h0 = 1.0 pairs

  float cstate = 1.0f;                             // leaders (tid&3)==0
  const __half* gp = gx + (size_t)b * T_ * G4_ + tid;   // permuted layout
  const uint4* wsrc = WP + 8 * 1024;               // streamed chunks 8..31

  for (int t = 0; t < T_; t++) {
    __syncthreads();

    // group A loads (chunks 8..15) + gate input
    uint4 ga[8];
#pragma unroll
    for (int i = 0; i < 8; i++) ga[i] = wsrc[i * 1024 + tid];
    float gxv = (float)*gp;
    gp += G4_;

    const half2_t* hb = (const half2_t*)hsU[t & 1];
    float a0 = 0.f, a1 = 0.f, a2 = 0.f, a3 = 0.f;

    // LDS part: chunks 0..7 (k2 0..31) — overlaps group A latency
#pragma unroll
    for (int i = 0; i < 8; i++) {
      U4H wc; wc.q = wl[i * 1024 + tid];
      half8_t hv = *(const half8_t*)(hb + i * 4);
      a0 = __builtin_amdgcn_fdot2(wc.h[0], ((half2_t*)&hv)[0], a0, false);
      a1 = __builtin_amdgcn_fdot2(wc.h[1], ((half2_t*)&hv)[1], a1, false);
      a2 = __builtin_amdgcn_fdot2(wc.h[2], ((half2_t*)&hv)[2], a2, false);
      a3 = __builtin_amdgcn_fdot2(wc.h[3], ((half2_t*)&hv)[3], a3, false);
    }

    // group B loads (chunks 16..23)
    uint4 gb[8];
#pragma unroll
    for (int i = 0; i < 8; i++) gb[i] = wsrc[(8 + i) * 1024 + tid];
    // compute group A (k2 32..63)
#pragma unroll
    for (int i = 0; i < 8; i++) {
      U4H wc; wc.q = ga[i];
      half8_t hv = *(const half8_t*)(hb + (8 + i) * 4);
      a0 = __builtin_amdgcn_fdot2(wc.h[0], ((half2_t*)&hv)[0], a0, false);
      a1 = __builtin_amdgcn_fdot2(wc.h[1], ((half2_t*)&hv)[1], a1, false);
      a2 = __builtin_amdgcn_fdot2(wc.h[2], ((half2_t*)&hv)[2], a2, false);
      a3 = __builtin_amdgcn_fdot2(wc.h[3], ((half2_t*)&hv)[3], a3, false);
    }

    // group C loads (chunks 24..31)
    uint4 gc[8];
#pragma unroll
    for (int i = 0; i < 8; i++) gc[i] = wsrc[(16 + i) * 1024 + tid];
    // compute group B (k2 64..95)
#pragma unroll
    for (int i = 0; i < 8; i++) {
      U4H wc; wc.q = gb[i];
      half8_t hv = *(const half8_t*)(hb + (16 + i) * 4);
      a0 = __builtin_amdgcn_fdot2(wc.h[0], ((half2_t*)&hv)[0], a0, false);
      a1 = __builtin_amdgcn_fdot2(wc.h[1], ((half2_t*)&hv)[1], a1, false);
      a2 = __builtin_amdgcn_fdot2(wc.h[2], ((half2_t*)&hv)[2], a2, false);
      a3 = __builtin_amdgcn_fdot2(wc.h[3], ((half2_t*)&hv)[3], a3, false);
    }
    // compute group C (k2 96..127)
#pragma unroll
    for (int i = 0; i < 8; i++) {
      U4H wc; wc.q = gc[i];
      half8_t hv = *(const half8_t*)(hb + (24 + i) * 4);
      a0 = __builtin_amdgcn_fdot2(wc.h[0], ((half2_t*)&hv)[0], a0, false);
      a1 = __builtin_amdgcn_fdot2(wc.h[1], ((half2_t*)&hv)[1], a1, false);
      a2 = __builtin_amdgcn_fdot2(wc.h[2], ((half2_t*)&hv)[2], a2, false);
      a3 = __builtin_amdgcn_fdot2(wc.h[3], ((half2_t*)&hv)[3], a3, false);
    }

    float s = ((a0 + a1) + (a2 + a3)) + gxv;

    // gates of a unit sit in adjacent lanes (tid&3 = gate)
    float s1 = __shfl_down(s, 1);
    float s2 = __shfl_down(s, 2);
    float s3 = __shfl_down(s, 3);
    if ((tid & 3) == 0) {
      float vi = fsigmoid(s);
      float vf = fsigmoid(s1);
      float vg = ftanh(s2);
      float vo = fsigmoid(s3);
      cstate = vf * cstate + vi * vg;
      float h = vo * ftanh(cstate);
      ((__half*)hsU[(t + 1) & 1])[unit] = __float2half(h);
      if (t == T_ - 1) hT[b * H_ + unit] = h;
    }
  }
}

// ---------------------------------------------------------------------------
// K6: logits = hT @ Wfc^T + bfc; softmax.  One wave per b.
// ---------------------------------------------------------------------------
__global__ __launch_bounds__(64) void k6_head(const float* __restrict__ hT,
                                              const float* __restrict__ Wfc,
                                              const float* __restrict__ bfc,
                                              float* __restrict__ out) {
  int b = blockIdx.x, l = threadIdx.x;
  const float* h = hT + b * H_;
  float p[C_];
#pragma unroll
  for (int c = 0; c < C_; c++) p[c] = 0.f;
#pragma unroll
  for (int q = 0; q < 4; q++) {
    float hv = h[q * 64 + l];
#pragma unroll
    for (int c = 0; c < C_; c++) p[c] += hv * Wfc[c * H_ + q * 64 + l];
  }
#pragma unroll
  for (int c = 0; c < C_; c++)
    for (int off = 32; off; off >>= 1) p[c] += __shfl_xor(p[c], off);
  if (l == 0) {
    float m = -1e30f, e[C_], sum = 0.f;
    for (int c = 0; c < C_; c++) { p[c] += bfc[c]; m = fmaxf(m, p[c]); }
    for (int c = 0; c < C_; c++) { e[c] = expf(p[c] - m); sum += e[c]; }
    for (int c = 0; c < C_; c++) out[b * C_ + c] = e[c] / sum;
  }
}

// ---------------------------------------------------------------------------
// Workspace layout (float offsets):
//   S     [B,R,T]        wsf + 0        (dead after k2; WP aliases it)
//   WP    [32][1024]u4   wsf + 0        (131072 dwords; written by k0b post-k2)
//   E     [B,R,T]        wsf + 655360
//   INVD  [B,R,T]        wsf + 1310720
//   M     [B,T,I]        wsf + 1966080
//   hT    [B,H]          wsf + 6160384
//   Wq    [1024][128]h2  wsf + 6176768  (131072 dwords)
//   gx    [B,T,4H] fp16  wsf + 6307840  (16777216 dwords)
//   P     [B][8][R][I]   aliases gx region (P dead before k4 writes gx)
// ---------------------------------------------------------------------------
extern "C" void kernel_launch(void* const* d_in, const int* in_sizes, int n_in,
                              void* d_out, int out_size, void* d_ws, size_t ws_size,
                              hipStream_t stream) {
  const float* x   = (const float*)d_in[0];
  const float* Wih = (const float*)d_in[1];
  const float* Whh = (const float*)d_in[2];
  const float* bg  = (const float*)d_in[3];
  const float* W1  = (const float*)d_in[4];
  const float* b1  = (const float*)d_in[5];
  const float* W2  = (const float*)d_in[6];
  const float* b2  = (const float*)d_in[7];
  const float* Wfc = (const float*)d_in[8];
  const float* bfc = (const float*)d_in[9];
  float* out = (float*)d_out;

  float* wsf = (float*)d_ws;
  float* S    = wsf;
  uint4* WP   = (uint4*)wsf;             // aliases S (S dead after k2)
  float* E    = wsf + 655360;
  float* INVD = wsf + 1310720;
  float* Mm   = wsf + 1966080;
  float* hT   = wsf + 6160384;
  half2_t* Wq = (half2_t*)(wsf + 6176768);
  __half* gx  = (__half*)(wsf + 6307840);
  float* P    = wsf + 6307840;           // aliases gx region (disjoint in time)

  hipLaunchKernelGGL(k0_pack,   dim3(512),     dim3(256),  0, stream, Whh, Wq);
  hipLaunchKernelGGL(k1_scores, dim3(512),     dim3(256),  0, stream, x, W1, b1, W2, b2, S);
  hipLaunchKernelGGL(k2_prefix, dim3(B_ * R_), dim3(64),   0, stream, S, E, INVD);
  hipLaunchKernelGGL(k0b_pack,  dim3(128),     dim3(256),  0, stream, Wq, WP);
  hipLaunchKernelGGL(k3a,       dim3(512),     dim3(128),  0, stream, x, E, P);
  hipLaunchKernelGGL(k3b,       dim3(640),     dim3(256),  0, stream, P);
  hipLaunchKernelGGL(k3c,       dim3(512),     dim3(128),  0, stream, x, E, INVD, P, Mm);
  hipLaunchKernelGGL(k4_gemm,   dim3(512, 16), dim3(256),  0, stream, Mm, Wih, bg, gx);
  hipLaunchKernelGGL(k5_lstm,   dim3(B_),      dim3(1024), 0, stream, gx, WP, hT);
  hipLaunchKernelGGL(k6_head,   dim3(B_),      dim3(64),   0, stream, hT, Wfc, bfc, out);
}